// Round 1
// baseline (933.536 us; speedup 1.0000x reference)
//
#include <hip/hip_runtime.h>

// ws float layout: [0:6] sum1, [6:12] sumsq1, [12:28] sum2, [28:44] sumsq2
#define WS_SUM1 0
#define WS_SQ1  6
#define WS_SUM2 12
#define WS_SQ2  28
#define WS_NFLOATS 44

__device__ __forceinline__ float wave_sum(float v) {
#pragma unroll
  for (int off = 32; off > 0; off >>= 1) v += __shfl_down(v, off, 64);
  return v;
}

// ---------------- Kernel A: conv1 raw-output statistics ----------------
__global__ __launch_bounds__(256) void k_stats1(
    const float* __restrict__ x, const float* __restrict__ w1,
    const float* __restrict__ b1, float* __restrict__ ws, int Btot) {
  const int t = blockIdx.x * 256 + threadIdx.x;
  float sum[6], sq[6];
#pragma unroll
  for (int c = 0; c < 6; ++c) { sum[c] = 0.f; sq[c] = 0.f; }

  if (t < Btot) {
    float xr[64];
    const float4* xp = reinterpret_cast<const float4*>(x + (size_t)t * 64);
#pragma unroll
    for (int i = 0; i < 16; ++i) {
      float4 v = xp[i];
      xr[4 * i + 0] = v.x; xr[4 * i + 1] = v.y;
      xr[4 * i + 2] = v.z; xr[4 * i + 3] = v.w;
    }
#pragma unroll
    for (int c = 0; c < 6; ++c) {
      float w[9];
#pragma unroll
      for (int k = 0; k < 9; ++k) w[k] = w1[c * 9 + k];
      const float bc = b1[c];
      float s = 0.f, q = 0.f;
#pragma unroll
      for (int i = 0; i < 10; ++i) {
#pragma unroll
        for (int j = 0; j < 10; ++j) {
          float y = bc;
#pragma unroll
          for (int u = 0; u < 3; ++u) {
            const int xi = i + u - 2;
            if (xi < 0 || xi > 7) continue;
#pragma unroll
            for (int v = 0; v < 3; ++v) {
              const int xj = j + v - 2;
              if (xj < 0 || xj > 7) continue;
              y = fmaf(w[u * 3 + v], xr[xi * 8 + xj], y);
            }
          }
          s += y;
          q = fmaf(y, y, q);
        }
      }
      sum[c] = s; sq[c] = q;
    }
  }

#pragma unroll
  for (int c = 0; c < 6; ++c) {
    const float s = wave_sum(sum[c]);
    const float q = wave_sum(sq[c]);
    if ((threadIdx.x & 63) == 0) {
      atomicAdd(&ws[WS_SUM1 + c], s);
      atomicAdd(&ws[WS_SQ1 + c], q);
    }
  }
}

// ---------------- shared front: conv1 + BN1 + ReLU + meanpool2 ----------------
__device__ __forceinline__ void pooled_front(
    const float* __restrict__ x, size_t t,
    const float* __restrict__ w1, const float* __restrict__ b1,
    const float* __restrict__ g1, const float* __restrict__ be1,
    const float* __restrict__ ws, float inv_n1, float p[6][5][5]) {
  float xr[64];
  const float4* xp = reinterpret_cast<const float4*>(x + t * 64);
#pragma unroll
  for (int i = 0; i < 16; ++i) {
    float4 v = xp[i];
    xr[4 * i + 0] = v.x; xr[4 * i + 1] = v.y;
    xr[4 * i + 2] = v.z; xr[4 * i + 3] = v.w;
  }
#pragma unroll
  for (int c = 0; c < 6; ++c) {
    float w[9];
#pragma unroll
    for (int k = 0; k < 9; ++k) w[k] = w1[c * 9 + k];
    const float bc = b1[c];
    // BN1 affine fold: z = y*sc + sh
    const float mean = ws[WS_SUM1 + c] * inv_n1;
    const float var  = ws[WS_SQ1 + c] * inv_n1 - mean * mean;
    const float sc   = g1[c] * rsqrtf(var + 1e-5f);
    const float sh   = be1[c] - mean * sc;
#pragma unroll
    for (int r = 0; r < 5; ++r) {
#pragma unroll
      for (int s = 0; s < 5; ++s) {
        float acc = 0.f;
#pragma unroll
        for (int di = 0; di < 2; ++di) {
#pragma unroll
          for (int dj = 0; dj < 2; ++dj) {
            const int i = 2 * r + di, j = 2 * s + dj;
            float y = bc;
#pragma unroll
            for (int u = 0; u < 3; ++u) {
              const int xi = i + u - 2;
              if (xi < 0 || xi > 7) continue;
#pragma unroll
              for (int v = 0; v < 3; ++v) {
                const int xj = j + v - 2;
                if (xj < 0 || xj > 7) continue;
                y = fmaf(w[u * 3 + v], xr[xi * 8 + xj], y);
              }
            }
            acc += fmaxf(fmaf(y, sc, sh), 0.f);
          }
        }
        p[c][r][s] = acc * 0.25f;
      }
    }
  }
}

// ---------------- Kernel B: conv2 output statistics ----------------
__global__ __launch_bounds__(256) void k_stats2(
    const float* __restrict__ x, const float* __restrict__ w1,
    const float* __restrict__ b1, const float* __restrict__ g1,
    const float* __restrict__ be1, const float* __restrict__ w2,
    const float* __restrict__ b2, float* __restrict__ ws,
    int Btot, float inv_n1) {
  const int t = blockIdx.x * 256 + threadIdx.x;
  float sum[16], sq[16];
#pragma unroll
  for (int o = 0; o < 16; ++o) { sum[o] = 0.f; sq[o] = 0.f; }

  if (t < Btot) {
    float p[6][5][5];
    pooled_front(x, (size_t)t, w1, b1, g1, be1, ws, inv_n1, p);
#pragma unroll
    for (int o = 0; o < 16; ++o) {
      float wv[24];
#pragma unroll
      for (int k = 0; k < 24; ++k) wv[k] = w2[o * 24 + k];
      const float bo = b2[o];
      float s = 0.f, q = 0.f;
#pragma unroll
      for (int i = 0; i < 4; ++i) {
#pragma unroll
        for (int j = 0; j < 4; ++j) {
          float y = bo;
#pragma unroll
          for (int c = 0; c < 6; ++c) {
#pragma unroll
            for (int u = 0; u < 2; ++u) {
#pragma unroll
              for (int v = 0; v < 2; ++v) {
                y = fmaf(wv[c * 4 + u * 2 + v], p[c][i + u][j + v], y);
              }
            }
          }
          s += y;
          q = fmaf(y, y, q);
        }
      }
      sum[o] = s; sq[o] = q;
    }
  }

#pragma unroll
  for (int o = 0; o < 16; ++o) {
    const float s = wave_sum(sum[o]);
    const float q = wave_sum(sq[o]);
    if ((threadIdx.x & 63) == 0) {
      atomicAdd(&ws[WS_SUM2 + o], s);
      atomicAdd(&ws[WS_SQ2 + o], q);
    }
  }
}

// ---------------- Kernel C: full forward ----------------
__global__ __launch_bounds__(256) void k_final(
    const float* __restrict__ x, const float* __restrict__ w1,
    const float* __restrict__ b1, const float* __restrict__ g1,
    const float* __restrict__ be1, const float* __restrict__ w2,
    const float* __restrict__ b2, const float* __restrict__ g2,
    const float* __restrict__ be2, const float* __restrict__ fw1,
    const float* __restrict__ fb1, const float* __restrict__ fw2,
    const float* __restrict__ fb2, const float* __restrict__ fw3,
    const float* __restrict__ fb3, const float* __restrict__ ws,
    float* __restrict__ out, int Btot, float inv_n1, float inv_n2) {
  const int t = blockIdx.x * 256 + threadIdx.x;
  if (t >= Btot) return;

  float p[6][5][5];
  pooled_front(x, (size_t)t, w1, b1, g1, be1, ws, inv_n1, p);

  float h[64];
#pragma unroll
  for (int o = 0; o < 16; ++o) {
    float wv[24];
#pragma unroll
    for (int k = 0; k < 24; ++k) wv[k] = w2[o * 24 + k];
    const float bo = b2[o];
    // BN2 affine fold (computed lazily per channel to save registers)
    const float mean = ws[WS_SUM2 + o] * inv_n2;
    const float var  = ws[WS_SQ2 + o] * inv_n2 - mean * mean;
    const float sc   = g2[o] * rsqrtf(var + 1e-5f);
    const float sh   = be2[o] - mean * sc;
#pragma unroll
    for (int si = 0; si < 2; ++si) {
#pragma unroll
      for (int sj = 0; sj < 2; ++sj) {
        float acc = 0.f;
#pragma unroll
        for (int di = 0; di < 2; ++di) {
#pragma unroll
          for (int dj = 0; dj < 2; ++dj) {
            const int i = 2 * si + di, j = 2 * sj + dj;
            float y = bo;
#pragma unroll
            for (int c = 0; c < 6; ++c) {
#pragma unroll
              for (int u = 0; u < 2; ++u) {
#pragma unroll
                for (int v = 0; v < 2; ++v) {
                  y = fmaf(wv[c * 4 + u * 2 + v], p[c][i + u][j + v], y);
                }
              }
            }
            acc += fmaxf(fmaf(y, sc, sh), 0.f);
          }
        }
        h[o * 4 + si * 2 + sj] = acc * 0.25f;
      }
    }
  }

  float a1[30];
#pragma unroll
  for (int o = 0; o < 30; ++o) {
    float acc = fb1[o];
#pragma unroll
    for (int j = 0; j < 64; ++j) acc = fmaf(fw1[o * 64 + j], h[j], acc);
    a1[o] = fmaxf(acc, 0.f);
  }

  float a2[15];
#pragma unroll
  for (int o = 0; o < 15; ++o) {
    float acc = fb2[o];
#pragma unroll
    for (int j = 0; j < 30; ++j) acc = fmaf(fw2[o * 30 + j], a1[j], acc);
    a2[o] = fmaxf(acc, 0.f);
  }

  float* op = out + (size_t)t * 10;
#pragma unroll
  for (int o = 0; o < 10; ++o) {
    float acc = fb3[o];
#pragma unroll
    for (int j = 0; j < 15; ++j) acc = fmaf(fw3[o * 15 + j], a2[j], acc);
    op[o] = acc;
  }
}

extern "C" void kernel_launch(void* const* d_in, const int* in_sizes, int n_in,
                              void* d_out, int out_size, void* d_ws, size_t ws_size,
                              hipStream_t stream) {
  (void)n_in; (void)out_size; (void)ws_size;
  const float* x   = (const float*)d_in[0];
  const float* w1  = (const float*)d_in[1];
  const float* b1  = (const float*)d_in[2];
  const float* g1  = (const float*)d_in[3];
  const float* be1 = (const float*)d_in[4];
  const float* w2  = (const float*)d_in[5];
  const float* b2  = (const float*)d_in[6];
  const float* g2  = (const float*)d_in[7];
  const float* be2 = (const float*)d_in[8];
  const float* fw1 = (const float*)d_in[9];
  const float* fb1 = (const float*)d_in[10];
  const float* fw2 = (const float*)d_in[11];
  const float* fb2 = (const float*)d_in[12];
  const float* fw3 = (const float*)d_in[13];
  const float* fb3 = (const float*)d_in[14];
  float* out = (float*)d_out;
  float* ws  = (float*)d_ws;

  const int Btot = in_sizes[0] / 64;
  const float inv_n1 = 1.0f / ((float)Btot * 100.0f);
  const float inv_n2 = 1.0f / ((float)Btot * 16.0f);
  const int grid = (Btot + 255) / 256;

  hipMemsetAsync(ws, 0, WS_NFLOATS * sizeof(float), stream);

  k_stats1<<<grid, 256, 0, stream>>>(x, w1, b1, ws, Btot);
  k_stats2<<<grid, 256, 0, stream>>>(x, w1, b1, g1, be1, w2, b2, ws, Btot, inv_n1);
  k_final<<<grid, 256, 0, stream>>>(x, w1, b1, g1, be1, w2, b2, g2, be2,
                                    fw1, fb1, fw2, fb2, fw3, fb3, ws, out,
                                    Btot, inv_n1, inv_n2);
}